// Round 3
// baseline (400.712 us; speedup 1.0000x reference)
//
#include <hip/hip_runtime.h>
#include <stdint.h>

#define D_IN 1280

typedef __attribute__((ext_vector_type(8))) short s16x8;
typedef __attribute__((ext_vector_type(4))) float f32x4;
typedef __attribute__((ext_vector_type(4))) unsigned int u32x4;

__device__ __forceinline__ unsigned short f2bf(float f) {
  union { float f; unsigned u; } v;
  v.f = f;
  unsigned u = v.u;
  return (unsigned short)((u + 0x7fffu + ((u >> 16) & 1u)) >> 16);  // RNE
}

__device__ __forceinline__ unsigned int cvtpk(float lo, float hi) {
  unsigned int r;
  asm("v_cvt_pk_bf16_f32 %0, %1, %2" : "=v"(r) : "v"(lo), "v"(hi));
  return r;  // low16 = bf16(lo), high16 = bf16(hi), RNE
}

__device__ __forceinline__ void gload_lds16(const void* g, void* l) {
  __builtin_amdgcn_global_load_lds(
      (const __attribute__((address_space(1))) void*)g,
      (__attribute__((address_space(3))) void*)l, 16, 0, 0);
}

// ---------------- Cayley: Q = (I - S) @ inv(I + S), S = 0.5(A - A^T) -------
__global__ void cayley_kernel(const float* __restrict__ A1,
                              const float* __restrict__ A2,
                              const float* __restrict__ A3,
                              float* __restrict__ qws) {
  const int which = blockIdx.x;
  const float* __restrict__ A = which == 0 ? A1 : (which == 1 ? A2 : A3);
  float* __restrict__ Q = which == 0 ? qws : (which == 1 ? qws + 16 : qws + 80);
  const int n = which == 0 ? 4 : (which == 1 ? 8 : 40);
  const int t = threadIdx.x;

  __shared__ float aug[40][80];
  __shared__ float Nm[40][40];
  __shared__ float fac[40];
  __shared__ int piv;

  for (int idx = t; idx < n * n; idx += 256) {
    int i = idx / n, j = idx % n;
    float s = 0.5f * (A[i * n + j] - A[j * n + i]);
    float eye = (i == j) ? 1.0f : 0.0f;
    aug[i][j] = eye + s;
    aug[i][n + j] = eye;
    Nm[i][j] = eye - s;
  }
  __syncthreads();

  for (int p = 0; p < n; ++p) {
    if (t == 0) {
      int best = p;
      float bv = fabsf(aug[p][p]);
      for (int i = p + 1; i < n; ++i) {
        float v = fabsf(aug[i][p]);
        if (v > bv) { bv = v; best = i; }
      }
      piv = best;
    }
    __syncthreads();
    const int pr = piv;
    if (pr != p) {
      for (int j = t; j < 2 * n; j += 256) {
        float tmp = aug[p][j];
        aug[p][j] = aug[pr][j];
        aug[pr][j] = tmp;
      }
    }
    __syncthreads();
    const float d = aug[p][p];
    __syncthreads();
    const float inv = 1.0f / d;
    for (int j = t; j < 2 * n; j += 256) aug[p][j] *= inv;
    __syncthreads();
    for (int i = t; i < n; i += 256) fac[i] = (i == p) ? 0.0f : aug[i][p];
    __syncthreads();
    for (int idx = t; idx < n * 2 * n; idx += 256) {
      int i = idx / (2 * n), j = idx % (2 * n);
      if (i != p) aug[i][j] -= fac[i] * aug[p][j];
    }
    __syncthreads();
  }

  for (int idx = t; idx < n * n; idx += 256) {
    int i = idx / n, j = idx % n;
    float acc = 0.0f;
    for (int k = 0; k < n; ++k) acc += Nm[i][k] * aug[k][n + j];
    Q[i * n + j] = acc;
  }
}

// ---------------- filt[o,:] = (q1 (x) q2 (x) q3) @ w_o, staged in LDS ------
__global__ void filt_kernel(const float* __restrict__ W,
                            const float* __restrict__ qws,
                            unsigned short* __restrict__ filt) {
  __shared__ float q1s[16];
  __shared__ float q2s[64];
  __shared__ float q3t[40][40];
  __shared__ float w[D_IN];
  __shared__ float t1[D_IN];
  __shared__ float t2[D_IN];
  const int t = threadIdx.x;
  const int o = blockIdx.x;

  if (t < 16) q1s[t] = qws[t];
  if (t < 64) q2s[t] = qws[16 + t];
  for (int k = t; k < 1600; k += 256) q3t[k % 40][k / 40] = qws[80 + k];
  const float4* __restrict__ wsrc = (const float4*)(W + (size_t)o * D_IN);
  for (int k = t; k < 320; k += 256) ((float4*)w)[k] = wsrc[k];
  __syncthreads();

  for (int e = t; e < D_IN; e += 256) {
    const int i3 = e % 40;
    const int b = e - i3;
    float s = 0.0f;
#pragma unroll
    for (int j3 = 0; j3 < 40; ++j3) s += w[b + j3] * q3t[j3][i3];
    t1[e] = s;
  }
  __syncthreads();

  for (int e = t; e < D_IN; e += 256) {
    const int i3 = e % 40;
    const int i2 = (e / 40) & 7;
    const int j1 = e / 320;
    float s = 0.0f;
#pragma unroll
    for (int j2 = 0; j2 < 8; ++j2) s += q2s[i2 * 8 + j2] * t1[j1 * 320 + j2 * 40 + i3];
    t2[e] = s;
  }
  __syncthreads();

  for (int e = t; e < D_IN; e += 256) {
    const int lo = e % 320;
    const int i1 = e / 320;
    float s = 0.0f;
#pragma unroll
    for (int j1 = 0; j1 < 4; ++j1) s += q1s[i1 * 4 + j1] * t2[j1 * 320 + lo];
    filt[(size_t)o * D_IN + e] = f2bf(s);
  }
}

// ---------------- main GEMM: out[m,n] = sum_k x[m,k] * filt[n,k] ------------
// M=32768, N=1280, K=1280. 128x128 tile, BK=64, 4 waves (each 64x64 as 4x4
// 16x16 frags x 2 k-frags). LDS XOR-swizzle slot'=slot^(row&7) on both A & B;
// B via global_load_lds with inverse-swizzled per-lane SOURCE (rule #21),
// A reg-staged fp32 -> v_cvt_pk_bf16_f32 -> swizzled ds_write_b128.
__global__ __launch_bounds__(256) void gemm_kernel(const float* __restrict__ x,
                                                   const unsigned short* __restrict__ filt,
                                                   float* __restrict__ out) {
  __shared__ short As[128][64];   // 16 KB, 128 B rows, swizzled
  __shared__ short Bs[128][64];   // 16 KB

  const int t = threadIdx.x;
  const int lane = t & 63;
  const int wave = t >> 6;
  const int wr = wave >> 1;
  const int wc = wave & 1;

  const int nwg = gridDim.x;                      // 2560, % 8 == 0
  const int bid = blockIdx.x;
  const int wg = (bid & 7) * (nwg >> 3) + (bid >> 3);  // bijective XCD swizzle
  const int mt = wg / 10;
  const int nt = wg % 10;
  const int mbase = mt * 128;
  const int nbase = nt * 128;

  f32x4 acc[4][4];
#pragma unroll
  for (int m = 0; m < 4; ++m)
#pragma unroll
    for (int n = 0; n < 4; ++n) acc[m][n] = 0.0f;

  // ---- A staging geometry: thread t owns row ar = t>>1, logical slots sb..sb+3
  // (slot = 16B = 8 shorts). Physical slot = slot ^ (ar&7).
  const int ar = t >> 1;
  const int sb = (t & 1) * 4;
  const float* __restrict__ asrc = x + (size_t)(mbase + ar) * D_IN + sb * 8;
  short* adst[4];
#pragma unroll
  for (int j = 0; j < 4; ++j) adst[j] = &As[ar][((sb + j) ^ (ar & 7)) * 8];

  // ---- B staging via global_load_lds: 4 issues of 4 KB. Linear LDS dest
  // byte = q*4096 + t*16 -> (row = q*32 + wave*8 + (lane>>3), phys slot = lane&7).
  // Source fetches the LOGICAL slot that belongs there: (lane&7)^(lane>>3).
  const int brow = wave * 8 + (lane >> 3);
  const int bcol = ((lane & 7) ^ (lane >> 3)) * 8;
  const unsigned short* __restrict__ bsrc[4];
  char* bdst[4];
#pragma unroll
  for (int q = 0; q < 4; ++q) {
    bsrc[q] = filt + (size_t)(nbase + q * 32 + brow) * D_IN + bcol;
    bdst[q] = (char*)Bs + q * 4096 + t * 16;
  }

  const int lr = lane & 15;
  const int hk = lane >> 4;   // 0..3 -> 16B slot within 32-wide k-frag

  for (int kt = 0; kt < D_IN; kt += 64) {
#pragma unroll
    for (int q = 0; q < 4; ++q) gload_lds16(bsrc[q] + kt, bdst[q]);

#pragma unroll
    for (int j = 0; j < 4; ++j) {
      const float* src = asrc + kt + j * 8;
      float4 f0 = *(const float4*)(src);
      float4 f1 = *(const float4*)(src + 4);
      u32x4 p;
      p[0] = cvtpk(f0.x, f0.y);
      p[1] = cvtpk(f0.z, f0.w);
      p[2] = cvtpk(f1.x, f1.y);
      p[3] = cvtpk(f1.z, f1.w);
      *(u32x4*)adst[j] = p;
    }

    __syncthreads();

#pragma unroll
    for (int kk = 0; kk < 2; ++kk) {
      s16x8 a[4], b[4];
#pragma unroll
      for (int m = 0; m < 4; ++m) {
        const int row = wr * 64 + m * 16 + lr;
        a[m] = *(const s16x8*)&As[row][((kk * 4 + hk) ^ (row & 7)) * 8];
      }
#pragma unroll
      for (int n = 0; n < 4; ++n) {
        const int row = wc * 64 + n * 16 + lr;
        b[n] = *(const s16x8*)&Bs[row][((kk * 4 + hk) ^ (row & 7)) * 8];
      }
#pragma unroll
      for (int m = 0; m < 4; ++m)
#pragma unroll
        for (int n = 0; n < 4; ++n)
          acc[m][n] = __builtin_amdgcn_mfma_f32_16x16x32_bf16(a[m], b[n], acc[m][n], 0, 0, 0);
    }

    __syncthreads();
  }

  // C/D layout: col = lane&15, row = (lane>>4)*4 + reg
  const int orow = (lane >> 4) << 2;
  const int ocol = lane & 15;
#pragma unroll
  for (int m = 0; m < 4; ++m) {
#pragma unroll
    for (int r = 0; r < 4; ++r) {
      float* cp = out + (size_t)(mbase + wr * 64 + m * 16 + orow + r) * D_IN +
                  nbase + wc * 64 + ocol;
#pragma unroll
      for (int n = 0; n < 4; ++n) cp[n * 16] = acc[m][n][r];
    }
  }
}

extern "C" void kernel_launch(void* const* d_in, const int* in_sizes, int n_in,
                              void* d_out, int out_size, void* d_ws, size_t ws_size,
                              hipStream_t stream) {
  (void)in_sizes; (void)n_in; (void)out_size; (void)ws_size;
  const float* x = (const float*)d_in[0];
  const float* k1 = (const float*)d_in[1];
  const float* k2 = (const float*)d_in[2];
  const float* k3 = (const float*)d_in[3];
  const float* W = (const float*)d_in[4];
  float* out = (float*)d_out;

  // ws layout: [0,8192) q1|q2|q3 (f32: 16 + 64 + 1600), [8192, +3.3MB) filt bf16
  float* qws = (float*)d_ws;
  unsigned short* filt = (unsigned short*)((char*)d_ws + 8192);

  cayley_kernel<<<3, 256, 0, stream>>>(k1, k2, k3, qws);
  filt_kernel<<<D_IN, 256, 0, stream>>>(W, qws, filt);
  gemm_kernel<<<2560, 256, 0, stream>>>(x, filt, out);
}

// Round 4
// 352.186 us; speedup vs baseline: 1.1378x; 1.1378x over previous
//
#include <hip/hip_runtime.h>
#include <stdint.h>

#define D_IN 1280

typedef __attribute__((ext_vector_type(8))) short s16x8;
typedef __attribute__((ext_vector_type(4))) float f32x4;
typedef __attribute__((ext_vector_type(4))) unsigned int u32x4;

__device__ __forceinline__ unsigned short f2bf(float f) {
  union { float f; unsigned u; } v;
  v.f = f;
  unsigned u = v.u;
  return (unsigned short)((u + 0x7fffu + ((u >> 16) & 1u)) >> 16);  // RNE
}

__device__ __forceinline__ unsigned int cvtpk(float lo, float hi) {
  unsigned int r;
  asm("v_cvt_pk_bf16_f32 %0, %1, %2" : "=v"(r) : "v"(lo), "v"(hi));
  return r;  // low16 = bf16(lo), high16 = bf16(hi), RNE
}

__device__ __forceinline__ void gload_lds16(const void* g, void* l) {
  __builtin_amdgcn_global_load_lds(
      (const __attribute__((address_space(1))) void*)g,
      (__attribute__((address_space(3))) void*)l, 16, 0, 0);
}

// ---------------- Cayley: Q = (I - S) @ inv(I + S), S = 0.5(A - A^T) -------
__global__ void cayley_kernel(const float* __restrict__ A1,
                              const float* __restrict__ A2,
                              const float* __restrict__ A3,
                              float* __restrict__ qws) {
  const int which = blockIdx.x;
  const float* __restrict__ A = which == 0 ? A1 : (which == 1 ? A2 : A3);
  float* __restrict__ Q = which == 0 ? qws : (which == 1 ? qws + 16 : qws + 80);
  const int n = which == 0 ? 4 : (which == 1 ? 8 : 40);
  const int t = threadIdx.x;

  __shared__ float aug[40][80];
  __shared__ float Nm[40][40];
  __shared__ float fac[40];
  __shared__ int piv;

  for (int idx = t; idx < n * n; idx += 256) {
    int i = idx / n, j = idx % n;
    float s = 0.5f * (A[i * n + j] - A[j * n + i]);
    float eye = (i == j) ? 1.0f : 0.0f;
    aug[i][j] = eye + s;
    aug[i][n + j] = eye;
    Nm[i][j] = eye - s;
  }
  __syncthreads();

  for (int p = 0; p < n; ++p) {
    if (t == 0) {
      int best = p;
      float bv = fabsf(aug[p][p]);
      for (int i = p + 1; i < n; ++i) {
        float v = fabsf(aug[i][p]);
        if (v > bv) { bv = v; best = i; }
      }
      piv = best;
    }
    __syncthreads();
    const int pr = piv;
    if (pr != p) {
      for (int j = t; j < 2 * n; j += 256) {
        float tmp = aug[p][j];
        aug[p][j] = aug[pr][j];
        aug[pr][j] = tmp;
      }
    }
    __syncthreads();
    const float d = aug[p][p];
    __syncthreads();
    const float inv = 1.0f / d;
    for (int j = t; j < 2 * n; j += 256) aug[p][j] *= inv;
    __syncthreads();
    for (int i = t; i < n; i += 256) fac[i] = (i == p) ? 0.0f : aug[i][p];
    __syncthreads();
    for (int idx = t; idx < n * 2 * n; idx += 256) {
      int i = idx / (2 * n), j = idx % (2 * n);
      if (i != p) aug[i][j] -= fac[i] * aug[p][j];
    }
    __syncthreads();
  }

  for (int idx = t; idx < n * n; idx += 256) {
    int i = idx / n, j = idx % n;
    float acc = 0.0f;
    for (int k = 0; k < n; ++k) acc += Nm[i][k] * aug[k][n + j];
    Q[i * n + j] = acc;
  }
}

// ---------------- filt[o,:] = (q1 (x) q2 (x) q3) @ w_o, staged in LDS ------
__global__ void filt_kernel(const float* __restrict__ W,
                            const float* __restrict__ qws,
                            unsigned short* __restrict__ filt) {
  __shared__ float q1s[16];
  __shared__ float q2s[64];
  __shared__ float q3t[40][40];
  __shared__ float w[D_IN];
  __shared__ float t1[D_IN];
  __shared__ float t2[D_IN];
  const int t = threadIdx.x;
  const int o = blockIdx.x;

  if (t < 16) q1s[t] = qws[t];
  if (t < 64) q2s[t] = qws[16 + t];
  for (int k = t; k < 1600; k += 256) q3t[k % 40][k / 40] = qws[80 + k];
  const float4* __restrict__ wsrc = (const float4*)(W + (size_t)o * D_IN);
  for (int k = t; k < 320; k += 256) ((float4*)w)[k] = wsrc[k];
  __syncthreads();

  for (int e = t; e < D_IN; e += 256) {
    const int i3 = e % 40;
    const int b = e - i3;
    float s = 0.0f;
#pragma unroll
    for (int j3 = 0; j3 < 40; ++j3) s += w[b + j3] * q3t[j3][i3];
    t1[e] = s;
  }
  __syncthreads();

  for (int e = t; e < D_IN; e += 256) {
    const int i3 = e % 40;
    const int i2 = (e / 40) & 7;
    const int j1 = e / 320;
    float s = 0.0f;
#pragma unroll
    for (int j2 = 0; j2 < 8; ++j2) s += q2s[i2 * 8 + j2] * t1[j1 * 320 + j2 * 40 + i3];
    t2[e] = s;
  }
  __syncthreads();

  for (int e = t; e < D_IN; e += 256) {
    const int lo = e % 320;
    const int i1 = e / 320;
    float s = 0.0f;
#pragma unroll
    for (int j1 = 0; j1 < 4; ++j1) s += q1s[i1 * 4 + j1] * t2[j1 * 320 + lo];
    filt[(size_t)o * D_IN + e] = f2bf(s);
  }
}

// ---------------- x (f32) -> xb (bf16), 41.94M elems, 8/thread -------------
__global__ __launch_bounds__(256) void cvt_kernel(const float* __restrict__ x,
                                                  unsigned short* __restrict__ xb) {
  const size_t i = ((size_t)blockIdx.x * 256 + threadIdx.x) * 8;
  float4 a = *(const float4*)(x + i);
  float4 b = *(const float4*)(x + i + 4);
  u32x4 p;
  p[0] = cvtpk(a.x, a.y);
  p[1] = cvtpk(a.z, a.w);
  p[2] = cvtpk(b.x, b.y);
  p[3] = cvtpk(b.z, b.w);
  *(u32x4*)(xb + i) = p;
}

// ---------------- main GEMM (pipelined): out[m,n] = sum_k xb[m,k]*filt[n,k] -
// BM=256, BN=128, BK=64. 8 waves (4M x 2N), each 64x64 = 4x4 frags x 2 kk.
// 3-deep K-tile LDS pipeline, counted vmcnt (12 = 2 K-tiles in flight), raw
// s_barrier (no compiler vmcnt(0) drain). XOR swizzle slot^(row&7), gload_lds
// with pre-swizzled per-lane source (R3-verified conflict-free machinery).
__global__ __launch_bounds__(512, 1) void gemm256_kernel(
    const unsigned short* __restrict__ xb,
    const unsigned short* __restrict__ filt,
    float* __restrict__ out) {
  __shared__ short As[3][256][64];   // 96 KB
  __shared__ short Bs[3][128][64];   // 48 KB

  const int t = threadIdx.x;
  const int lane = t & 63;
  const int wave = t >> 6;
  const int wr = wave >> 1;          // 0..3 -> 64-row slice of BM=256
  const int wc = wave & 1;           // 0..1 -> 64-col slice of BN=128

  const int nwg = gridDim.x;         // 1280, % 8 == 0
  const int bid = blockIdx.x;
  const int wg = (bid & 7) * (nwg >> 3) + (bid >> 3);  // bijective XCD swizzle
  const int mt = wg / 10;
  const int nt = wg % 10;
  const int mbase = mt * 256;
  const int nbase = nt * 128;

  f32x4 acc[4][4];
#pragma unroll
  for (int m = 0; m < 4; ++m)
#pragma unroll
    for (int n = 0; n < 4; ++n) acc[m][n] = 0.0f;

  // Staging geometry: thread t covers dest byte t*16 (+ q*8192): row = 64q + (t>>3),
  // phys slot = t&7. Source fetches logical slot (t&7)^(row&7); (row&7)=(t>>3)&7.
  const int tr = t >> 3;                                   // 0..63
  const int scol = (((t & 7) ^ (tr & 7)) << 3);            // source col (elems)
  const unsigned short* __restrict__ asrc = xb + (size_t)(mbase + tr) * D_IN + scol;
  const unsigned short* __restrict__ bsrc = filt + (size_t)(nbase + tr) * D_IN + scol;

#define STAGE(KT, BUF)                                                        \
  {                                                                           \
    const int _ko = (KT) * 64;                                                \
    _Pragma("unroll")                                                         \
    for (int q = 0; q < 4; ++q)                                               \
      gload_lds16(asrc + (size_t)q * 64 * D_IN + _ko,                         \
                  (void*)&As[BUF][64 * q + tr][(t & 7) << 3]);                \
    _Pragma("unroll")                                                         \
    for (int q = 0; q < 2; ++q)                                               \
      gload_lds16(bsrc + (size_t)q * 64 * D_IN + _ko,                         \
                  (void*)&Bs[BUF][64 * q + tr][(t & 7) << 3]);                \
  }

  const int lr = lane & 15;
  const int hk = lane >> 4;   // 0..3 -> 16B slot within 32-wide k-frag

  // Prologue: fill 2 tiles (12 loads in flight).
  STAGE(0, 0);
  STAGE(1, 1);

  for (int k = 0; k < 20; ++k) {
    const int buf = k % 3;
    if (k <= 17) STAGE(k + 2, (k + 2) % 3);
    if (k <= 17)      asm volatile("s_waitcnt vmcnt(12)" ::: "memory");
    else if (k == 18) asm volatile("s_waitcnt vmcnt(6)" ::: "memory");
    else              asm volatile("s_waitcnt vmcnt(0)" ::: "memory");
    asm volatile("s_barrier" ::: "memory");   // tile k resident everywhere

    s16x8 a0[4], b0[4], a1[4], b1[4];
#pragma unroll
    for (int m = 0; m < 4; ++m) {
      const int row = wr * 64 + m * 16 + lr;
      a0[m] = *(const s16x8*)&As[buf][row][(hk ^ (row & 7)) << 3];
      a1[m] = *(const s16x8*)&As[buf][row][((4 + hk) ^ (row & 7)) << 3];
    }
#pragma unroll
    for (int n = 0; n < 4; ++n) {
      const int row = wc * 64 + n * 16 + lr;
      b0[n] = *(const s16x8*)&Bs[buf][row][(hk ^ (row & 7)) << 3];
      b1[n] = *(const s16x8*)&Bs[buf][row][((4 + hk) ^ (row & 7)) << 3];
    }

    __builtin_amdgcn_s_setprio(1);
#pragma unroll
    for (int m = 0; m < 4; ++m)
#pragma unroll
      for (int n = 0; n < 4; ++n)
        acc[m][n] = __builtin_amdgcn_mfma_f32_16x16x32_bf16(a0[m], b0[n], acc[m][n], 0, 0, 0);
    __builtin_amdgcn_s_setprio(0);

    // All of this wave's reads of buf done -> after barrier, buf may be restaged.
    asm volatile("s_waitcnt lgkmcnt(0)" ::: "memory");
    asm volatile("s_barrier" ::: "memory");

    __builtin_amdgcn_s_setprio(1);
#pragma unroll
    for (int m = 0; m < 4; ++m)
#pragma unroll
      for (int n = 0; n < 4; ++n)
        acc[m][n] = __builtin_amdgcn_mfma_f32_16x16x32_bf16(a1[m], b1[n], acc[m][n], 0, 0, 0);
    __builtin_amdgcn_s_setprio(0);
  }
#undef STAGE

  // C/D layout: col = lane&15, row = (lane>>4)*4 + reg
  const int orow = (lane >> 4) << 2;
  const int ocol = lane & 15;
#pragma unroll
  for (int m = 0; m < 4; ++m) {
#pragma unroll
    for (int r = 0; r < 4; ++r) {
      float* cp = out + (size_t)(mbase + wr * 64 + m * 16 + orow + r) * D_IN +
                  nbase + wc * 64 + ocol;
#pragma unroll
      for (int n = 0; n < 4; ++n) cp[n * 16] = acc[m][n][r];
    }
  }
}

// ---------------- fallback GEMM (R2 structure, fused f32->bf16 A) ----------
__global__ __launch_bounds__(256) void gemm_fb_kernel(const float* __restrict__ x,
                                                      const unsigned short* __restrict__ filt,
                                                      float* __restrict__ out) {
  __shared__ short As[128][32];
  __shared__ short Bs[128][32];

  const int t = threadIdx.x;
  const int lane = t & 63;
  const int wave = t >> 6;
  const int wr = wave >> 1;
  const int wc = wave & 1;

  const int nwg = gridDim.x;
  const int bid = blockIdx.x;
  const int wg = (bid & 7) * (nwg >> 3) + (bid >> 3);
  const int mt = wg / 10;
  const int nt = wg % 10;
  const int mbase = mt * 128;
  const int nbase = nt * 128;

  f32x4 acc[4][4];
#pragma unroll
  for (int m = 0; m < 4; ++m)
#pragma unroll
    for (int n = 0; n < 4; ++n) acc[m][n] = 0.0f;

  const int ar = t >> 1;
  const int ac = (t & 1) << 4;
  const float* __restrict__ asrc = x + (size_t)(mbase + ar) * D_IN + ac;

  const int br = t >> 2;
  const int bc = (t & 3) << 3;
  const unsigned short* __restrict__ bsrc0 = filt + (size_t)(nbase + br) * D_IN + bc;
  const unsigned short* __restrict__ bsrc1 = filt + (size_t)(nbase + br + 64) * D_IN + bc;
  short* bdst0 = &Bs[br][bc];
  short* bdst1 = &Bs[br + 64][bc];

  const int lr = lane & 15;
  const int lk = (lane >> 4) << 3;

  for (int kt = 0; kt < D_IN; kt += 32) {
    gload_lds16(bsrc0 + kt, bdst0);
    gload_lds16(bsrc1 + kt, bdst1);

    const float* src = asrc + kt;
    float4 f0 = *(const float4*)(src + 0);
    float4 f1 = *(const float4*)(src + 4);
    float4 f2 = *(const float4*)(src + 8);
    float4 f3 = *(const float4*)(src + 12);
    u32x4 p0, p1;
    p0[0] = cvtpk(f0.x, f0.y); p0[1] = cvtpk(f0.z, f0.w);
    p0[2] = cvtpk(f1.x, f1.y); p0[3] = cvtpk(f1.z, f1.w);
    p1[0] = cvtpk(f2.x, f2.y); p1[1] = cvtpk(f2.z, f2.w);
    p1[2] = cvtpk(f3.x, f3.y); p1[3] = cvtpk(f3.z, f3.w);
    *(u32x4*)&As[ar][ac] = p0;
    *(u32x4*)&As[ar][ac + 16] = p1;

    __syncthreads();

    s16x8 a[4], b[4];
#pragma unroll
    for (int m = 0; m < 4; ++m)
      a[m] = *(const s16x8*)&As[wr * 64 + m * 16 + lr][lk];
#pragma unroll
    for (int n = 0; n < 4; ++n)
      b[n] = *(const s16x8*)&Bs[wc * 64 + n * 16 + lr][lk];
#pragma unroll
    for (int m = 0; m < 4; ++m)
#pragma unroll
      for (int n = 0; n < 4; ++n)
        acc[m][n] = __builtin_amdgcn_mfma_f32_16x16x32_bf16(a[m], b[n], acc[m][n], 0, 0, 0);

    __syncthreads();
  }

  const int orow = (lane >> 4) << 2;
  const int ocol = lane & 15;
#pragma unroll
  for (int m = 0; m < 4; ++m) {
#pragma unroll
    for (int r = 0; r < 4; ++r) {
      float* cp = out + (size_t)(mbase + wr * 64 + m * 16 + orow + r) * D_IN +
                  nbase + wc * 64 + ocol;
#pragma unroll
      for (int n = 0; n < 4; ++n) cp[n * 16] = acc[m][n][r];
    }
  }
}

extern "C" void kernel_launch(void* const* d_in, const int* in_sizes, int n_in,
                              void* d_out, int out_size, void* d_ws, size_t ws_size,
                              hipStream_t stream) {
  (void)in_sizes; (void)n_in; (void)out_size;
  const float* x = (const float*)d_in[0];
  const float* k1 = (const float*)d_in[1];
  const float* k2 = (const float*)d_in[2];
  const float* k3 = (const float*)d_in[3];
  const float* W = (const float*)d_in[4];
  float* out = (float*)d_out;

  // ws layout: [0,8KB) q1|q2|q3 f32; [8KB, 8KB+3.28MB) filt bf16;
  // [4MB, 4MB+83.9MB) xb bf16 (fast path only).
  float* qws = (float*)d_ws;
  unsigned short* filt = (unsigned short*)((char*)d_ws + 8192);
  unsigned short* xb = (unsigned short*)((char*)d_ws + (4u << 20));
  const size_t need = (4ull << 20) + (size_t)32768 * D_IN * 2;

  cayley_kernel<<<3, 256, 0, stream>>>(k1, k2, k3, qws);
  filt_kernel<<<D_IN, 256, 0, stream>>>(W, qws, filt);

  if (ws_size >= need) {
    cvt_kernel<<<20480, 256, 0, stream>>>(x, xb);           // 32768*1280/8/256
    gemm256_kernel<<<1280, 512, 0, stream>>>(xb, filt, out);
  } else {
    gemm_fb_kernel<<<2560, 256, 0, stream>>>(x, filt, out);
  }
}

// Round 6
// 321.600 us; speedup vs baseline: 1.2460x; 1.0951x over previous
//
#include <hip/hip_runtime.h>
#include <stdint.h>

#define D_IN 1280

typedef __attribute__((ext_vector_type(8))) short s16x8;
typedef __attribute__((ext_vector_type(4))) float f32x4;
typedef __attribute__((ext_vector_type(4))) unsigned int u32x4;

__device__ __forceinline__ unsigned short f2bf(float f) {
  union { float f; unsigned u; } v;
  v.f = f;
  unsigned u = v.u;
  return (unsigned short)((u + 0x7fffu + ((u >> 16) & 1u)) >> 16);  // RNE
}

__device__ __forceinline__ unsigned int cvtpk(float lo, float hi) {
  unsigned int r;
  asm("v_cvt_pk_bf16_f32 %0, %1, %2" : "=v"(r) : "v"(lo), "v"(hi));
  return r;
}

__device__ __forceinline__ void gload_lds16(const void* g, void* l) {
  __builtin_amdgcn_global_load_lds(
      (const __attribute__((address_space(1))) void*)g,
      (__attribute__((address_space(3))) void*)l, 16, 0, 0);
}

// ---------------- Cayley: Q = (I - S) @ inv(I + S), S = 0.5(A - A^T) -------
__global__ void cayley_kernel(const float* __restrict__ A1,
                              const float* __restrict__ A2,
                              const float* __restrict__ A3,
                              float* __restrict__ qws) {
  const int which = blockIdx.x;
  const float* __restrict__ A = which == 0 ? A1 : (which == 1 ? A2 : A3);
  float* __restrict__ Q = which == 0 ? qws : (which == 1 ? qws + 16 : qws + 80);
  const int n = which == 0 ? 4 : (which == 1 ? 8 : 40);
  const int t = threadIdx.x;

  __shared__ float aug[40][80];
  __shared__ float Nm[40][40];
  __shared__ float fac[40];
  __shared__ int piv;

  for (int idx = t; idx < n * n; idx += 256) {
    int i = idx / n, j = idx % n;
    float s = 0.5f * (A[i * n + j] - A[j * n + i]);
    float eye = (i == j) ? 1.0f : 0.0f;
    aug[i][j] = eye + s;
    aug[i][n + j] = eye;
    Nm[i][j] = eye - s;
  }
  __syncthreads();

  for (int p = 0; p < n; ++p) {
    if (t == 0) {
      int best = p;
      float bv = fabsf(aug[p][p]);
      for (int i = p + 1; i < n; ++i) {
        float v = fabsf(aug[i][p]);
        if (v > bv) { bv = v; best = i; }
      }
      piv = best;
    }
    __syncthreads();
    const int pr = piv;
    if (pr != p) {
      for (int j = t; j < 2 * n; j += 256) {
        float tmp = aug[p][j];
        aug[p][j] = aug[pr][j];
        aug[pr][j] = tmp;
      }
    }
    __syncthreads();
    const float d = aug[p][p];
    __syncthreads();
    const float inv = 1.0f / d;
    for (int j = t; j < 2 * n; j += 256) aug[p][j] *= inv;
    __syncthreads();
    for (int i = t; i < n; i += 256) fac[i] = (i == p) ? 0.0f : aug[i][p];
    __syncthreads();
    for (int idx = t; idx < n * 2 * n; idx += 256) {
      int i = idx / (2 * n), j = idx % (2 * n);
      if (i != p) aug[i][j] -= fac[i] * aug[p][j];
    }
    __syncthreads();
  }

  for (int idx = t; idx < n * n; idx += 256) {
    int i = idx / n, j = idx % n;
    float acc = 0.0f;
    for (int k = 0; k < n; ++k) acc += Nm[i][k] * aug[k][n + j];
    Q[i * n + j] = acc;
  }
}

// ---------------- filt: 4 o-rows per block, staged Kronecker apply ---------
#define FROWS 4
__global__ void filt_kernel(const float* __restrict__ W,
                            const float* __restrict__ qws,
                            unsigned short* __restrict__ filt) {
  __shared__ float q1s[16];
  __shared__ float q2s[64];
  __shared__ float q3t[40][40];
  __shared__ float w[FROWS][D_IN];
  __shared__ float t1[FROWS][D_IN];
  __shared__ float t2[FROWS][D_IN];
  const int t = threadIdx.x;
  const int ob = blockIdx.x * FROWS;

  if (t < 16) q1s[t] = qws[t];
  if (t < 64) q2s[t] = qws[16 + t];
  for (int k = t; k < 1600; k += 256) q3t[k % 40][k / 40] = qws[80 + k];
  for (int k = t; k < FROWS * 320; k += 256) {
    int r = k / 320, c = k % 320;
    ((float4*)w[r])[c] = ((const float4*)(W + (size_t)(ob + r) * D_IN))[c];
  }
  __syncthreads();

  for (int e = t; e < FROWS * D_IN; e += 256) {
    const int r = e / D_IN;
    const int i = e - r * D_IN;
    const int i3 = i % 40;
    const int b = i - i3;
    float s = 0.0f;
#pragma unroll
    for (int j3 = 0; j3 < 40; ++j3) s += w[r][b + j3] * q3t[j3][i3];
    t1[r][i] = s;
  }
  __syncthreads();

  for (int e = t; e < FROWS * D_IN; e += 256) {
    const int r = e / D_IN;
    const int i = e - r * D_IN;
    const int i3 = i % 40;
    const int i2 = (i / 40) & 7;
    const int j1 = i / 320;
    float s = 0.0f;
#pragma unroll
    for (int j2 = 0; j2 < 8; ++j2) s += q2s[i2 * 8 + j2] * t1[r][j1 * 320 + j2 * 40 + i3];
    t2[r][i] = s;
  }
  __syncthreads();

  for (int e = t; e < FROWS * D_IN; e += 256) {
    const int r = e / D_IN;
    const int i = e - r * D_IN;
    const int lo = i % 320;
    const int i1 = i / 320;
    float s = 0.0f;
#pragma unroll
    for (int j1 = 0; j1 < 4; ++j1) s += q1s[i1 * 4 + j1] * t2[r][j1 * 320 + lo];
    filt[(size_t)(ob + r) * D_IN + i] = f2bf(s);
  }
}

// ---------------- x (f32) -> xb (bf16) -------------------------------------
__global__ __launch_bounds__(256) void cvt_kernel(const float* __restrict__ x,
                                                  unsigned short* __restrict__ xb) {
  const size_t i = ((size_t)blockIdx.x * 256 + threadIdx.x) * 8;
  float4 a = *(const float4*)(x + i);
  float4 b = *(const float4*)(x + i + 4);
  u32x4 p;
  p[0] = cvtpk(a.x, a.y);
  p[1] = cvtpk(a.z, a.w);
  p[2] = cvtpk(b.x, b.y);
  p[3] = cvtpk(b.z, b.w);
  *(u32x4*)(xb + i) = p;
}

// ---------------- main GEMM: 8-phase (m201-style port), RACE-FIXED ---------
// BM=BN=256, BK=64, 8 waves (2M x 4N), per-wave 128x64. LDS = 2dbuf x 2half
// x (A,B) = 128 KB. One half-tile stage (2 gload_lds) per phase.
// INVARIANT (R5 bug fix): the counted vmcnt for tile j+1's loads is placed at
// the END of tile j's phase 3, BEFORE the closing s_barrier — so the barrier
// certifies ALL waves' staging loads complete before any wave issues tile
// j+1's ds_reads. (vmcnt is per-wave; a vmcnt directly before the reads only
// covers the issuing wave's loads — that was the R5 NaN race.)
// Count audit: at end-of-ph3 of tile j, per-wave outstanding = tile j+1's 8
// loads (A h0 from j-1 ph3 leftover, A h1 ph0, B h0 ph1, B h1 ph2) + tile
// j+2's A h0 (ph3, 2 loads) -> vmcnt(2) drains exactly tile j+1.
__global__ __launch_bounds__(512, 2) void gemm8p_kernel(
    const unsigned short* __restrict__ xb,
    const unsigned short* __restrict__ filt,
    float* __restrict__ out) {
  __shared__ short As[2][2][128][64];   // 64 KB
  __shared__ short Bs[2][2][128][64];   // 64 KB

  const int t = threadIdx.x;
  const int lane = t & 63;
  const int wave = t >> 6;
  const int wr = wave >> 2;          // 0..1: M half (128 rows)
  const int wc = wave & 3;           // 0..3: N slice (64 cols)
  const int hb = wc >> 1;            // B half
  const int nloc = (wc & 1) * 64;    // row base within B half

  const int nwg = gridDim.x;         // 640, % 8 == 0
  const int bid = blockIdx.x;
  const int wg = (bid & 7) * (nwg >> 3) + (bid >> 3);  // bijective XCD swizzle
  const int mt = wg / 5;
  const int nt = wg % 5;
  const int mbase = mt * 256;
  const int nbase = nt * 256;

  f32x4 acc[8][4];
#pragma unroll
  for (int m = 0; m < 8; ++m)
#pragma unroll
    for (int n = 0; n < 4; ++n) acc[m][n] = 0.0f;

  // Staging geometry (rule #21): dest linear in lane (base + lane*16);
  // source pre-swizzled: logical slot = (t&7) ^ (row&7), row&7 = (t>>3)&7.
  const int tr = t >> 3;                        // 0..63
  const int scol = (((t & 7) ^ (tr & 7)) << 3); // source col (elems)
  const int pslot = (t & 7) << 3;               // dest col (elems)
  const unsigned short* __restrict__ abase = xb + (size_t)mbase * D_IN + scol;
  const unsigned short* __restrict__ bbase = filt + (size_t)nbase * D_IN + scol;

#define STAGE_A(P, H, KT)                                                     \
  {                                                                           \
    _Pragma("unroll")                                                         \
    for (int q = 0; q < 2; ++q)                                               \
      gload_lds16(abase + (size_t)((H)*128 + q * 64 + tr) * D_IN + (KT)*64,   \
                  (void*)&As[P][H][q * 64 + tr][pslot]);                      \
  }
#define STAGE_B(P, H, KT)                                                     \
  {                                                                           \
    _Pragma("unroll")                                                         \
    for (int q = 0; q < 2; ++q)                                               \
      gload_lds16(bbase + (size_t)((H)*128 + q * 64 + tr) * D_IN + (KT)*64,   \
                  (void*)&Bs[P][H][q * 64 + tr][pslot]);                      \
  }

  const int lr = lane & 15;
  const int hk = lane >> 4;          // 0..3
  const int c0 = ((hk ^ (lr & 7)) << 3);        // phys col, kk=0 (elems)
  const int c1 = c0 ^ 32;                       // phys col, kk=1

#define BAR asm volatile("s_barrier" ::: "memory")
#define LGKM0 asm volatile("s_waitcnt lgkmcnt(0)" ::: "memory")

  // Prologue: tile0 A+B (8 loads), tile1 A-half0 (2 loads); then certify
  // tile0 resident for ALL waves before any ds_read.
  STAGE_A(0, 0, 0); STAGE_A(0, 1, 0);
  STAGE_B(0, 0, 0); STAGE_B(0, 1, 0);
  STAGE_A(1, 0, 1);
  asm volatile("s_waitcnt vmcnt(2)" ::: "memory");
  BAR;

  s16x8 aLo[8], aHi[8], bLo[4], bHi[4];

#pragma unroll 2
  for (int j = 0; j < 20; ++j) {
    const int d = j & 1;

    // ---- phase 0: Q(m0-3, n0-1). reads aLo(8) + bLo(4); stage As[d^1][1].
#pragma unroll
    for (int m = 0; m < 4; ++m) {
      aLo[m * 2 + 0] = *(const s16x8*)&As[d][wr][m * 16 + lr][c0];
      aLo[m * 2 + 1] = *(const s16x8*)&As[d][wr][m * 16 + lr][c1];
    }
#pragma unroll
    for (int n = 0; n < 2; ++n) {
      bLo[n * 2 + 0] = *(const s16x8*)&Bs[d][hb][nloc + n * 16 + lr][c0];
      bLo[n * 2 + 1] = *(const s16x8*)&Bs[d][hb][nloc + n * 16 + lr][c1];
    }
    if (j < 19) STAGE_A(d ^ 1, 1, j + 1);
    BAR; LGKM0;
    __builtin_amdgcn_s_setprio(1);
#pragma unroll
    for (int m = 0; m < 4; ++m)
#pragma unroll
      for (int n = 0; n < 2; ++n)
#pragma unroll
        for (int kk = 0; kk < 2; ++kk)
          acc[m][n] = __builtin_amdgcn_mfma_f32_16x16x32_bf16(
              aLo[m * 2 + kk], bLo[n * 2 + kk], acc[m][n], 0, 0, 0);
    __builtin_amdgcn_s_setprio(0);
    BAR;

    // ---- phase 1: Q(m0-3, n2-3). reads bHi(4); stage Bs[d^1][0].
#pragma unroll
    for (int n = 0; n < 2; ++n) {
      bHi[n * 2 + 0] = *(const s16x8*)&Bs[d][hb][nloc + (n + 2) * 16 + lr][c0];
      bHi[n * 2 + 1] = *(const s16x8*)&Bs[d][hb][nloc + (n + 2) * 16 + lr][c1];
    }
    if (j < 19) STAGE_B(d ^ 1, 0, j + 1);
    BAR; LGKM0;
    __builtin_amdgcn_s_setprio(1);
#pragma unroll
    for (int m = 0; m < 4; ++m)
#pragma unroll
      for (int n = 0; n < 2; ++n)
#pragma unroll
        for (int kk = 0; kk < 2; ++kk)
          acc[m][n + 2] = __builtin_amdgcn_mfma_f32_16x16x32_bf16(
              aLo[m * 2 + kk], bHi[n * 2 + kk], acc[m][n + 2], 0, 0, 0);
    __builtin_amdgcn_s_setprio(0);
    BAR;

    // ---- phase 2: Q(m4-7, n2-3). reads aHi(8); stage Bs[d^1][1].
#pragma unroll
    for (int m = 0; m < 4; ++m) {
      aHi[m * 2 + 0] = *(const s16x8*)&As[d][wr][(m + 4) * 16 + lr][c0];
      aHi[m * 2 + 1] = *(const s16x8*)&As[d][wr][(m + 4) * 16 + lr][c1];
    }
    if (j < 19) STAGE_B(d ^ 1, 1, j + 1);
    BAR; LGKM0;
    __builtin_amdgcn_s_setprio(1);
#pragma unroll
    for (int m = 0; m < 4; ++m)
#pragma unroll
      for (int n = 0; n < 2; ++n)
#pragma unroll
        for (int kk = 0; kk < 2; ++kk)
          acc[m + 4][n + 2] = __builtin_amdgcn_mfma_f32_16x16x32_bf16(
              aHi[m * 2 + kk], bHi[n * 2 + kk], acc[m + 4][n + 2], 0, 0, 0);
    __builtin_amdgcn_s_setprio(0);
    BAR;

    // ---- phase 3: Q(m4-7, n0-1). no reads; stage As[d][0] for tile j+2.
    // End of this phase: counted vmcnt BEFORE the closing barrier certifies
    // tile j+1 resident (all waves) for the next iteration's ds_reads.
    if (j < 18) STAGE_A(d, 0, j + 2);
    BAR;
    __builtin_amdgcn_s_setprio(1);
#pragma unroll
    for (int m = 0; m < 4; ++m)
#pragma unroll
      for (int n = 0; n < 2; ++n)
#pragma unroll
        for (int kk = 0; kk < 2; ++kk)
          acc[m + 4][n] = __builtin_amdgcn_mfma_f32_16x16x32_bf16(
              aHi[m * 2 + kk], bLo[n * 2 + kk], acc[m + 4][n], 0, 0, 0);
    __builtin_amdgcn_s_setprio(0);
    if (j <= 17)      asm volatile("s_waitcnt vmcnt(2)" ::: "memory");
    else if (j == 18) asm volatile("s_waitcnt vmcnt(0)" ::: "memory");
    BAR;
  }
#undef STAGE_A
#undef STAGE_B
#undef BAR
#undef LGKM0

  // C/D layout: col = lane&15, row = (lane>>4)*4 + reg
  const int orow = (lane >> 4) << 2;
  const int ocol = lane & 15;
#pragma unroll
  for (int m = 0; m < 8; ++m) {
#pragma unroll
    for (int r = 0; r < 4; ++r) {
      float* cp = out + (size_t)(mbase + wr * 128 + m * 16 + orow + r) * D_IN +
                  nbase + wc * 64 + ocol;
#pragma unroll
      for (int n = 0; n < 4; ++n) cp[n * 16] = acc[m][n][r];
    }
  }
}

// ---------------- fallback GEMM (R2 structure, fused f32->bf16 A) ----------
__global__ __launch_bounds__(256) void gemm_fb_kernel(const float* __restrict__ x,
                                                      const unsigned short* __restrict__ filt,
                                                      float* __restrict__ out) {
  __shared__ short As[128][32];
  __shared__ short Bs[128][32];

  const int t = threadIdx.x;
  const int lane = t & 63;
  const int wave = t >> 6;
  const int wr = wave >> 1;
  const int wc = wave & 1;

  const int nwg = gridDim.x;
  const int bid = blockIdx.x;
  const int wg = (bid & 7) * (nwg >> 3) + (bid >> 3);
  const int mt = wg / 10;
  const int nt = wg % 10;
  const int mbase = mt * 128;
  const int nbase = nt * 128;

  f32x4 acc[4][4];
#pragma unroll
  for (int m = 0; m < 4; ++m)
#pragma unroll
    for (int n = 0; n < 4; ++n) acc[m][n] = 0.0f;

  const int ar = t >> 1;
  const int ac = (t & 1) << 4;
  const float* __restrict__ asrc = x + (size_t)(mbase + ar) * D_IN + ac;

  const int br = t >> 2;
  const int bc = (t & 3) << 3;
  const unsigned short* __restrict__ bsrc0 = filt + (size_t)(nbase + br) * D_IN + bc;
  const unsigned short* __restrict__ bsrc1 = filt + (size_t)(nbase + br + 64) * D_IN + bc;
  short* bdst0 = &Bs[br][bc];
  short* bdst1 = &Bs[br + 64][bc];

  const int lr = lane & 15;
  const int lk = (lane >> 4) << 3;

  for (int kt = 0; kt < D_IN; kt += 32) {
    gload_lds16(bsrc0 + kt, bdst0);
    gload_lds16(bsrc1 + kt, bdst1);

    const float* src = asrc + kt;
    float4 f0 = *(const float4*)(src + 0);
    float4 f1 = *(const float4*)(src + 4);
    float4 f2 = *(const float4*)(src + 8);
    float4 f3 = *(const float4*)(src + 12);
    u32x4 p0, p1;
    p0[0] = cvtpk(f0.x, f0.y); p0[1] = cvtpk(f0.z, f0.w);
    p0[2] = cvtpk(f1.x, f1.y); p0[3] = cvtpk(f1.z, f1.w);
    p1[0] = cvtpk(f2.x, f2.y); p1[1] = cvtpk(f2.z, f2.w);
    p1[2] = cvtpk(f3.x, f3.y); p1[3] = cvtpk(f3.z, f3.w);
    *(u32x4*)&As[ar][ac] = p0;
    *(u32x4*)&As[ar][ac + 16] = p1;

    __syncthreads();

    s16x8 a[4], b[4];
#pragma unroll
    for (int m = 0; m < 4; ++m)
      a[m] = *(const s16x8*)&As[wr * 64 + m * 16 + lr][lk];
#pragma unroll
    for (int n = 0; n < 4; ++n)
      b[n] = *(const s16x8*)&Bs[wc * 64 + n * 16 + lr][lk];
#pragma unroll
    for (int m = 0; m < 4; ++m)
#pragma unroll
      for (int n = 0; n < 4; ++n)
        acc[m][n] = __builtin_amdgcn_mfma_f32_16x16x32_bf16(a[m], b[n], acc[m][n], 0, 0, 0);

    __syncthreads();
  }

  const int orow = (lane >> 4) << 2;
  const int ocol = lane & 15;
#pragma unroll
  for (int m = 0; m < 4; ++m) {
#pragma unroll
    for (int r = 0; r < 4; ++r) {
      float* cp = out + (size_t)(mbase + wr * 64 + m * 16 + orow + r) * D_IN +
                  nbase + wc * 64 + ocol;
#pragma unroll
      for (int n = 0; n < 4; ++n) cp[n * 16] = acc[m][n][r];
    }
  }
}

extern "C" void kernel_launch(void* const* d_in, const int* in_sizes, int n_in,
                              void* d_out, int out_size, void* d_ws, size_t ws_size,
                              hipStream_t stream) {
  (void)in_sizes; (void)n_in; (void)out_size;
  const float* x = (const float*)d_in[0];
  const float* k1 = (const float*)d_in[1];
  const float* k2 = (const float*)d_in[2];
  const float* k3 = (const float*)d_in[3];
  const float* W = (const float*)d_in[4];
  float* out = (float*)d_out;

  // ws layout: [0,8KB) q1|q2|q3 f32; [8KB,+3.28MB) filt bf16; [4MB,+83.9MB) xb.
  float* qws = (float*)d_ws;
  unsigned short* filt = (unsigned short*)((char*)d_ws + 8192);
  unsigned short* xb = (unsigned short*)((char*)d_ws + (4u << 20));
  const size_t need = (4ull << 20) + (size_t)32768 * D_IN * 2;

  cayley_kernel<<<3, 256, 0, stream>>>(k1, k2, k3, qws);
  filt_kernel<<<D_IN / FROWS, 256, 0, stream>>>(W, qws, filt);

  if (ws_size >= need) {
    cvt_kernel<<<20480, 256, 0, stream>>>(x, xb);
    gemm8p_kernel<<<640, 512, 0, stream>>>(xb, filt, out);
  } else {
    gemm_fb_kernel<<<2560, 256, 0, stream>>>(x, filt, out);
  }
}

// Round 8
// 268.254 us; speedup vs baseline: 1.4938x; 1.1989x over previous
//
#include <hip/hip_runtime.h>
#include <stdint.h>

#define D_IN 1280

typedef __attribute__((ext_vector_type(8))) short s16x8;
typedef __attribute__((ext_vector_type(4))) float f32x4;
typedef __attribute__((ext_vector_type(4))) unsigned int u32x4;

__device__ __forceinline__ unsigned short f2bf(float f) {
  union { float f; unsigned u; } v;
  v.f = f;
  unsigned u = v.u;
  return (unsigned short)((u + 0x7fffu + ((u >> 16) & 1u)) >> 16);  // RNE
}

__device__ __forceinline__ unsigned int cvtpk(float lo, float hi) {
  unsigned int r;
  asm("v_cvt_pk_bf16_f32 %0, %1, %2" : "=v"(r) : "v"(lo), "v"(hi));
  return r;
}

__device__ __forceinline__ void gload_lds16(const void* g, void* l) {
  __builtin_amdgcn_global_load_lds(
      (const __attribute__((address_space(1))) void*)g,
      (__attribute__((address_space(3))) void*)l, 16, 0, 0);
}

// ---------------- Cayley: Q = (I - S) @ inv(I + S), S = 0.5(A - A^T) -------
// NO PIVOTING: for M = I + S (S skew), every GJ divisor is a Schur-complement
// diagonal of the form 1 + sum(s^2) >= 1 — stable without pivoting.
__global__ void cayley_kernel(const float* __restrict__ A1,
                              const float* __restrict__ A2,
                              const float* __restrict__ A3,
                              float* __restrict__ qws) {
  const int which = blockIdx.x;
  const float* __restrict__ A = which == 0 ? A1 : (which == 1 ? A2 : A3);
  float* __restrict__ Q = which == 0 ? qws : (which == 1 ? qws + 16 : qws + 80);
  const int n = which == 0 ? 4 : (which == 1 ? 8 : 40);
  const int t = threadIdx.x;

  __shared__ float aug[40][80];
  __shared__ float Nm[40][40];
  __shared__ float fac[40];

  for (int idx = t; idx < n * n; idx += 256) {
    int i = idx / n, j = idx % n;
    float s = 0.5f * (A[i * n + j] - A[j * n + i]);
    float eye = (i == j) ? 1.0f : 0.0f;
    aug[i][j] = eye + s;        // M = I + S
    aug[i][n + j] = eye;        // augmented identity
    Nm[i][j] = eye - s;         // N = I - S
  }
  __syncthreads();

  for (int p = 0; p < n; ++p) {
    const float d = aug[p][p];                       // broadcast read
    if (t < n) fac[t] = (t == p) ? 0.0f : aug[t][p]; // snapshot col p
    __syncthreads();                                 // d+fac read before writes
    const float inv = 1.0f / d;
    if (t < 2 * n) aug[p][t] *= inv;
    __syncthreads();                                 // scaled row p visible
    for (int idx = t; idx < n * 2 * n; idx += 256) {
      int i = idx / (2 * n), j = idx % (2 * n);
      aug[i][j] -= fac[i] * aug[p][j];               // i==p: fac=0, no-op
    }
    __syncthreads();
  }

  // Q = Nm @ Minv  (Minv = aug[:, n:2n])
  for (int idx = t; idx < n * n; idx += 256) {
    int i = idx / n, j = idx % n;
    float acc = 0.0f;
    for (int k = 0; k < n; ++k) acc += Nm[i][k] * aug[k][n + j];
    Q[i * n + j] = acc;
  }
}

// ---------------- filt: 4 o-rows per block, staged Kronecker apply ---------
// 320 threads. Step A holds ROW i3 of q3 in registers (thread t owns
// i3 = t%40): s += w[b+j3] * q3[i3][j3]. (R7 bug: loaded column -> q3^T.)
#define FROWS 4
__global__ __launch_bounds__(320) void filt_kernel(const float* __restrict__ W,
                                                   const float* __restrict__ qws,
                                                   unsigned short* __restrict__ filt) {
  __shared__ float q1s[16];
  __shared__ float q2s[64];
  __shared__ float w[FROWS][D_IN];
  __shared__ float t1[FROWS][D_IN];
  __shared__ float t2[FROWS][D_IN];
  const int t = threadIdx.x;
  const int ob = blockIdx.x * FROWS;

  if (t < 16) q1s[t] = qws[t];
  if (t < 64) q2s[t] = qws[16 + t];

  // q3 ROW i3 into registers: q3c[j3] = q3[i3][j3] = qws[80 + i3*40 + j3].
  const int i3 = t % 40;
  const int g = t / 40;  // 0..7
  float q3c[40];
#pragma unroll
  for (int j3 = 0; j3 < 40; ++j3) q3c[j3] = qws[80 + i3 * 40 + j3];

  for (int k = t; k < FROWS * 320; k += 320) {
    int r = k / 320, c = k % 320;
    ((float4*)w[r])[c] = ((const float4*)(W + (size_t)(ob + r) * D_IN))[c];
  }
  __syncthreads();

  // step A: t1[r][b+i3] = sum_j3 w[r][b+j3] * q3[i3][j3].
  // 128 items (r in 4, b-group in 32) over 8 thread-groups of 40 lanes.
#pragma unroll
  for (int kk = 0; kk < 16; ++kk) {
    const int item = g * 16 + kk;
    const int r = item >> 5;
    const int b = (item & 31) * 40;
    float s = 0.0f;
#pragma unroll
    for (int j3 = 0; j3 < 40; ++j3) s += w[r][b + j3] * q3c[j3];
    t1[r][b + i3] = s;
  }
  __syncthreads();

  // step B: t2[r][j1*320 + i2*40 + i3] = sum_j2 q2[i2*8+j2] * t1[r][j1*320+j2*40+i3]
  for (int e = t; e < FROWS * D_IN; e += 320) {
    const int r = e / D_IN;
    const int i = e - r * D_IN;
    const int ii3 = i % 40;
    const int i2 = (i / 40) & 7;
    const int j1 = i / 320;
    float s = 0.0f;
#pragma unroll
    for (int j2 = 0; j2 < 8; ++j2) s += q2s[i2 * 8 + j2] * t1[r][j1 * 320 + j2 * 40 + ii3];
    t2[r][i] = s;
  }
  __syncthreads();

  // step C: filt[o, i1*320 + lo] = sum_j1 q1[i1*4+j1] * t2[r][j1*320 + lo]
  for (int e = t; e < FROWS * D_IN; e += 320) {
    const int r = e / D_IN;
    const int i = e - r * D_IN;
    const int lo = i % 320;
    const int i1 = i / 320;
    float s = 0.0f;
#pragma unroll
    for (int j1 = 0; j1 < 4; ++j1) s += q1s[i1 * 4 + j1] * t2[r][j1 * 320 + lo];
    filt[(size_t)(ob + r) * D_IN + i] = f2bf(s);
  }
}

// ---------------- x (f32) -> xb (bf16) -------------------------------------
__global__ __launch_bounds__(256) void cvt_kernel(const float* __restrict__ x,
                                                  unsigned short* __restrict__ xb) {
  const size_t i = ((size_t)blockIdx.x * 256 + threadIdx.x) * 8;
  float4 a = *(const float4*)(x + i);
  float4 b = *(const float4*)(x + i + 4);
  u32x4 p;
  p[0] = cvtpk(a.x, a.y);
  p[1] = cvtpk(a.z, a.w);
  p[2] = cvtpk(b.x, b.y);
  p[3] = cvtpk(b.z, b.w);
  *(u32x4*)(xb + i) = p;
}

// ---------------- main GEMM: 8-phase (m201-style port), RACE-FIXED ---------
// (unchanged from R6 — verified PASS at 150.4 us, 714 TF, 0 bank conflicts)
__global__ __launch_bounds__(512, 2) void gemm8p_kernel(
    const unsigned short* __restrict__ xb,
    const unsigned short* __restrict__ filt,
    float* __restrict__ out) {
  __shared__ short As[2][2][128][64];   // 64 KB
  __shared__ short Bs[2][2][128][64];   // 64 KB

  const int t = threadIdx.x;
  const int lane = t & 63;
  const int wave = t >> 6;
  const int wr = wave >> 2;          // 0..1: M half (128 rows)
  const int wc = wave & 3;           // 0..3: N slice (64 cols)
  const int hb = wc >> 1;            // B half
  const int nloc = (wc & 1) * 64;    // row base within B half

  const int nwg = gridDim.x;         // 640, % 8 == 0
  const int bid = blockIdx.x;
  const int wg = (bid & 7) * (nwg >> 3) + (bid >> 3);  // bijective XCD swizzle
  const int mt = wg / 5;
  const int nt = wg % 5;
  const int mbase = mt * 256;
  const int nbase = nt * 256;

  f32x4 acc[8][4];
#pragma unroll
  for (int m = 0; m < 8; ++m)
#pragma unroll
    for (int n = 0; n < 4; ++n) acc[m][n] = 0.0f;

  const int tr = t >> 3;                        // 0..63
  const int scol = (((t & 7) ^ (tr & 7)) << 3); // source col (elems)
  const int pslot = (t & 7) << 3;               // dest col (elems)
  const unsigned short* __restrict__ abase = xb + (size_t)mbase * D_IN + scol;
  const unsigned short* __restrict__ bbase = filt + (size_t)nbase * D_IN + scol;

#define STAGE_A(P, H, KT)                                                     \
  {                                                                           \
    _Pragma("unroll")                                                         \
    for (int q = 0; q < 2; ++q)                                               \
      gload_lds16(abase + (size_t)((H)*128 + q * 64 + tr) * D_IN + (KT)*64,   \
                  (void*)&As[P][H][q * 64 + tr][pslot]);                      \
  }
#define STAGE_B(P, H, KT)                                                     \
  {                                                                           \
    _Pragma("unroll")                                                         \
    for (int q = 0; q < 2; ++q)                                               \
      gload_lds16(bbase + (size_t)((H)*128 + q * 64 + tr) * D_IN + (KT)*64,   \
                  (void*)&Bs[P][H][q * 64 + tr][pslot]);                      \
  }

  const int lr = lane & 15;
  const int hk = lane >> 4;          // 0..3
  const int c0 = ((hk ^ (lr & 7)) << 3);        // phys col, kk=0 (elems)
  const int c1 = c0 ^ 32;                       // phys col, kk=1

#define BAR asm volatile("s_barrier" ::: "memory")
#define LGKM0 asm volatile("s_waitcnt lgkmcnt(0)" ::: "memory")

  STAGE_A(0, 0, 0); STAGE_A(0, 1, 0);
  STAGE_B(0, 0, 0); STAGE_B(0, 1, 0);
  STAGE_A(1, 0, 1);
  asm volatile("s_waitcnt vmcnt(2)" ::: "memory");
  BAR;

  s16x8 aLo[8], aHi[8], bLo[4], bHi[4];

#pragma unroll 2
  for (int j = 0; j < 20; ++j) {
    const int d = j & 1;

    // ---- phase 0: Q(m0-3, n0-1). reads aLo(8) + bLo(4); stage As[d^1][1].
#pragma unroll
    for (int m = 0; m < 4; ++m) {
      aLo[m * 2 + 0] = *(const s16x8*)&As[d][wr][m * 16 + lr][c0];
      aLo[m * 2 + 1] = *(const s16x8*)&As[d][wr][m * 16 + lr][c1];
    }
#pragma unroll
    for (int n = 0; n < 2; ++n) {
      bLo[n * 2 + 0] = *(const s16x8*)&Bs[d][hb][nloc + n * 16 + lr][c0];
      bLo[n * 2 + 1] = *(const s16x8*)&Bs[d][hb][nloc + n * 16 + lr][c1];
    }
    if (j < 19) STAGE_A(d ^ 1, 1, j + 1);
    BAR; LGKM0;
    __builtin_amdgcn_s_setprio(1);
#pragma unroll
    for (int m = 0; m < 4; ++m)
#pragma unroll
      for (int n = 0; n < 2; ++n)
#pragma unroll
        for (int kk = 0; kk < 2; ++kk)
          acc[m][n] = __builtin_amdgcn_mfma_f32_16x16x32_bf16(
              aLo[m * 2 + kk], bLo[n * 2 + kk], acc[m][n], 0, 0, 0);
    __builtin_amdgcn_s_setprio(0);
    BAR;

    // ---- phase 1: Q(m0-3, n2-3). reads bHi(4); stage Bs[d^1][0].
#pragma unroll
    for (int n = 0; n < 2; ++n) {
      bHi[n * 2 + 0] = *(const s16x8*)&Bs[d][hb][nloc + (n + 2) * 16 + lr][c0];
      bHi[n * 2 + 1] = *(const s16x8*)&Bs[d][hb][nloc + (n + 2) * 16 + lr][c1];
    }
    if (j < 19) STAGE_B(d ^ 1, 0, j + 1);
    BAR; LGKM0;
    __builtin_amdgcn_s_setprio(1);
#pragma unroll
    for (int m = 0; m < 4; ++m)
#pragma unroll
      for (int n = 0; n < 2; ++n)
#pragma unroll
        for (int kk = 0; kk < 2; ++kk)
          acc[m][n + 2] = __builtin_amdgcn_mfma_f32_16x16x32_bf16(
              aLo[m * 2 + kk], bHi[n * 2 + kk], acc[m][n + 2], 0, 0, 0);
    __builtin_amdgcn_s_setprio(0);
    BAR;

    // ---- phase 2: Q(m4-7, n2-3). reads aHi(8); stage Bs[d^1][1].
#pragma unroll
    for (int m = 0; m < 4; ++m) {
      aHi[m * 2 + 0] = *(const s16x8*)&As[d][wr][(m + 4) * 16 + lr][c0];
      aHi[m * 2 + 1] = *(const s16x8*)&As[d][wr][(m + 4) * 16 + lr][c1];
    }
    if (j < 19) STAGE_B(d ^ 1, 1, j + 1);
    BAR; LGKM0;
    __builtin_amdgcn_s_setprio(1);
#pragma unroll
    for (int m = 0; m < 4; ++m)
#pragma unroll
      for (int n = 0; n < 2; ++n)
#pragma unroll
        for (int kk = 0; kk < 2; ++kk)
          acc[m + 4][n + 2] = __builtin_amdgcn_mfma_f32_16x16x32_bf16(
              aHi[m * 2 + kk], bHi[n * 2 + kk], acc[m + 4][n + 2], 0, 0, 0);
    __builtin_amdgcn_s_setprio(0);
    BAR;

    // ---- phase 3: Q(m4-7, n0-1). stage As[d][0] for tile j+2; counted
    // vmcnt BEFORE closing barrier certifies tile j+1 resident for ALL waves.
    if (j < 18) STAGE_A(d, 0, j + 2);
    BAR;
    __builtin_amdgcn_s_setprio(1);
#pragma unroll
    for (int m = 0; m < 4; ++m)
#pragma unroll
      for (int n = 0; n < 2; ++n)
#pragma unroll
        for (int kk = 0; kk < 2; ++kk)
          acc[m + 4][n] = __builtin_amdgcn_mfma_f32_16x16x32_bf16(
              aHi[m * 2 + kk], bLo[n * 2 + kk], acc[m + 4][n], 0, 0, 0);
    __builtin_amdgcn_s_setprio(0);
    if (j <= 17)      asm volatile("s_waitcnt vmcnt(2)" ::: "memory");
    else if (j == 18) asm volatile("s_waitcnt vmcnt(0)" ::: "memory");
    BAR;
  }
#undef STAGE_A
#undef STAGE_B
#undef BAR
#undef LGKM0

  const int orow = (lane >> 4) << 2;
  const int ocol = lane & 15;
#pragma unroll
  for (int m = 0; m < 8; ++m) {
#pragma unroll
    for (int r = 0; r < 4; ++r) {
      float* cp = out + (size_t)(mbase + wr * 128 + m * 16 + orow + r) * D_IN +
                  nbase + wc * 64 + ocol;
#pragma unroll
      for (int n = 0; n < 4; ++n) cp[n * 16] = acc[m][n][r];
    }
  }
}

// ---------------- fallback GEMM (R2 structure, fused f32->bf16 A) ----------
__global__ __launch_bounds__(256) void gemm_fb_kernel(const float* __restrict__ x,
                                                      const unsigned short* __restrict__ filt,
                                                      float* __restrict__ out) {
  __shared__ short As[128][32];
  __shared__ short Bs[128][32];

  const int t = threadIdx.x;
  const int lane = t & 63;
  const int wave = t >> 6;
  const int wr = wave >> 1;
  const int wc = wave & 1;

  const int nwg = gridDim.x;
  const int bid = blockIdx.x;
  const int wg = (bid & 7) * (nwg >> 3) + (bid >> 3);
  const int mt = wg / 10;
  const int nt = wg % 10;
  const int mbase = mt * 128;
  const int nbase = nt * 128;

  f32x4 acc[4][4];
#pragma unroll
  for (int m = 0; m < 4; ++m)
#pragma unroll
    for (int n = 0; n < 4; ++n) acc[m][n] = 0.0f;

  const int ar = t >> 1;
  const int ac = (t & 1) << 4;
  const float* __restrict__ asrc = x + (size_t)(mbase + ar) * D_IN + ac;

  const int br = t >> 2;
  const int bc = (t & 3) << 3;
  const unsigned short* __restrict__ bsrc0 = filt + (size_t)(nbase + br) * D_IN + bc;
  const unsigned short* __restrict__ bsrc1 = filt + (size_t)(nbase + br + 64) * D_IN + bc;
  short* bdst0 = &Bs[br][bc];
  short* bdst1 = &Bs[br + 64][bc];

  const int lr = lane & 15;
  const int lk = (lane >> 4) << 3;

  for (int kt = 0; kt < D_IN; kt += 32) {
    gload_lds16(bsrc0 + kt, bdst0);
    gload_lds16(bsrc1 + kt, bdst1);

    const float* src = asrc + kt;
    float4 f0 = *(const float4*)(src + 0);
    float4 f1 = *(const float4*)(src + 4);
    float4 f2 = *(const float4*)(src + 8);
    float4 f3 = *(const float4*)(src + 12);
    u32x4 p0, p1;
    p0[0] = cvtpk(f0.x, f0.y); p0[1] = cvtpk(f0.z, f0.w);
    p0[2] = cvtpk(f1.x, f1.y); p0[3] = cvtpk(f1.z, f1.w);
    p1[0] = cvtpk(f2.x, f2.y); p1[1] = cvtpk(f2.z, f2.w);
    p1[2] = cvtpk(f3.x, f3.y); p1[3] = cvtpk(f3.z, f3.w);
    *(u32x4*)&As[ar][ac] = p0;
    *(u32x4*)&As[ar][ac + 16] = p1;

    __syncthreads();

    s16x8 a[4], b[4];
#pragma unroll
    for (int m = 0; m < 4; ++m)
      a[m] = *(const s16x8*)&As[wr * 64 + m * 16 + lr][lk];
#pragma unroll
    for (int n = 0; n < 4; ++n)
      b[n] = *(const s16x8*)&Bs[wc * 64 + n * 16 + lr][lk];
#pragma unroll
    for (int m = 0; m < 4; ++m)
#pragma unroll
      for (int n = 0; n < 4; ++n)
        acc[m][n] = __builtin_amdgcn_mfma_f32_16x16x32_bf16(a[m], b[n], acc[m][n], 0, 0, 0);

    __syncthreads();
  }

  const int orow = (lane >> 4) << 2;
  const int ocol = lane & 15;
#pragma unroll
  for (int m = 0; m < 4; ++m) {
#pragma unroll
    for (int r = 0; r < 4; ++r) {
      float* cp = out + (size_t)(mbase + wr * 64 + m * 16 + orow + r) * D_IN +
                  nbase + wc * 64 + ocol;
#pragma unroll
      for (int n = 0; n < 4; ++n) cp[n * 16] = acc[m][n][r];
    }
  }
}

extern "C" void kernel_launch(void* const* d_in, const int* in_sizes, int n_in,
                              void* d_out, int out_size, void* d_ws, size_t ws_size,
                              hipStream_t stream) {
  (void)in_sizes; (void)n_in; (void)out_size;
  const float* x = (const float*)d_in[0];
  const float* k1 = (const float*)d_in[1];
  const float* k2 = (const float*)d_in[2];
  const float* k3 = (const float*)d_in[3];
  const float* W = (const float*)d_in[4];
  float* out = (float*)d_out;

  // ws layout: [0,8KB) q1|q2|q3 f32; [8KB,+3.28MB) filt bf16; [4MB,+83.9MB) xb.
  float* qws = (float*)d_ws;
  unsigned short* filt = (unsigned short*)((char*)d_ws + 8192);
  unsigned short* xb = (unsigned short*)((char*)d_ws + (4u << 20));
  const size_t need = (4ull << 20) + (size_t)32768 * D_IN * 2;

  cayley_kernel<<<3, 256, 0, stream>>>(k1, k2, k3, qws);
  filt_kernel<<<D_IN / FROWS, 320, 0, stream>>>(W, qws, filt);

  if (ws_size >= need) {
    cvt_kernel<<<20480, 256, 0, stream>>>(x, xb);
    gemm8p_kernel<<<640, 512, 0, stream>>>(xb, filt, out);
  } else {
    gemm_fb_kernel<<<2560, 256, 0, stream>>>(x, filt, out);
  }
}